// Round 1
// baseline (116.333 us; speedup 1.0000x reference)
//
#include <hip/hip_runtime.h>
#include <hip/hip_bf16.h>
#include <math.h>

#define BS    128
#define NC    1024
#define UNITS 512
#define FEAT  512
#define FOURU 2048

typedef short bf16x8 __attribute__((ext_vector_type(8)));
typedef float f32x4  __attribute__((ext_vector_type(4)));

__device__ __forceinline__ short f2bf(float f) {
    union { float f; unsigned int u; } v; v.f = f;
    unsigned int r = (v.u + 0x7fffu + ((v.u >> 16) & 1u)) >> 16;
    return (short)r;
}

// ---------------- K1: per-row argmax of class_logits (== hard softmax) ----
__global__ __launch_bounds__(256) void argmax_kernel(
    const float* __restrict__ logits, int* __restrict__ sidx)
{
    int b = blockIdx.x;
    int t = threadIdx.x;
    float best = -INFINITY; int bi = 0;
    for (int i = t; i < NC; i += 256) {
        float v = logits[b * NC + i];
        if (v > best) { best = v; bi = i; }
    }
    for (int off = 32; off > 0; off >>= 1) {
        float ov = __shfl_down(best, off);
        int   oi = __shfl_down(bi, off);
        if (ov > best || (ov == best && oi < bi)) { best = ov; bi = oi; }
    }
    __shared__ float sv[4]; __shared__ int si[4];
    int wid = t >> 6;
    if ((t & 63) == 0) { sv[wid] = best; si[wid] = bi; }
    __syncthreads();
    if (t == 0) {
        for (int w = 1; w < 4; ++w)
            if (sv[w] > best || (sv[w] == best && si[w] < bi)) { best = sv[w]; bi = si[w]; }
        sidx[b] = bi;
    }
}

// ---------------- K2: z += A-slice @ W-slice via bf16 MFMA ----------------
// Block: 256 threads (4 waves). Tile: M=128 (all rows), N=32, K-group=256.
// grid = (64 n-tiles, 4 k-groups). Partial sums combined with atomicAdd into
// a zeroed z buffer. A = [x | h_states[idx]] along k.
#define NT   32
#define KC   32
#define APAD 40   // padded bf16 row stride: 80 B, 16B-aligned, 4-way max conflict

__global__ __launch_bounds__(256) void gemm_kernel(
    const float* __restrict__ x, const float* __restrict__ h_states,
    const float* __restrict__ kern, const float* __restrict__ reck,
    const int* __restrict__ sidx, float* __restrict__ z)
{
    __shared__ __align__(16) short as[BS * APAD];     // A chunk 128 x 32 bf16
    __shared__ __align__(16) short wst[NT * APAD];    // W chunk transposed: [n][k]
    __shared__ int sIdx[BS];

    int t = threadIdx.x;
    int ntile = blockIdx.x * NT;
    int kg = blockIdx.y;                  // 0..3, each covers 256 of k=1024
    int kbase = kg * 256;
    bool useH = (kg >= 2);
    const float* W = useH ? reck : kern;
    int wkbase = useH ? (kbase - 512) : kbase;   // k within the source matrix

    if (t < BS) sIdx[t] = sidx[t];
    __syncthreads();

    int wid = t >> 6, lane = t & 63;
    int l15 = lane & 15, quad = lane >> 4;

    f32x4 zero = {0.f, 0.f, 0.f, 0.f};
    f32x4 acc[2][2] = {{zero, zero}, {zero, zero}};

    for (int kstep = 0; kstep < 8; ++kstep) {
        int wk0 = wkbase + kstep * KC;    // k offset inside x/h_states and W

        // stage A: 128 x 32 f32 -> bf16, 8 f32x2 per thread
        {
            int k2 = (t & 15) * 2;
            int mb = t >> 4;
            for (int p = 0; p < 8; ++p) {
                int m = mb + p * 16;
                const float* src = useH ? (h_states + (long)sIdx[m] * UNITS + wk0 + k2)
                                        : (x + (long)m * FEAT + wk0 + k2);
                float2 v = *(const float2*)src;
                unsigned int pk = ((unsigned int)(unsigned short)f2bf(v.x)) |
                                  (((unsigned int)(unsigned short)f2bf(v.y)) << 16);
                *(unsigned int*)&as[m * APAD + k2] = pk;
            }
        }
        // stage W^T: 32k x 32n -> wst[n][k]
        {
            int n  = t & 31;
            int kk0 = t >> 5;
            for (int p = 0; p < 4; ++p) {
                int kk = kk0 + p * 8;
                wst[n * APAD + kk] = f2bf(W[(long)(wk0 + kk) * FOURU + ntile + n]);
            }
        }
        __syncthreads();

        bf16x8 afrag[2], bfrag[2];
        for (int ms = 0; ms < 2; ++ms) {
            int m = wid * 32 + ms * 16 + l15;
            afrag[ms] = *(const bf16x8*)&as[m * APAD + quad * 8];
        }
        for (int ns = 0; ns < 2; ++ns) {
            int n = ns * 16 + l15;
            bfrag[ns] = *(const bf16x8*)&wst[n * APAD + quad * 8];
        }
        for (int ms = 0; ms < 2; ++ms)
            for (int ns = 0; ns < 2; ++ns)
                acc[ms][ns] = __builtin_amdgcn_mfma_f32_16x16x32_bf16(
                                  afrag[ms], bfrag[ns], acc[ms][ns], 0, 0, 0);
        __syncthreads();
    }

    // C/D layout (verified m89): col = lane&15, row = (lane>>4)*4 + reg
    for (int ms = 0; ms < 2; ++ms)
        for (int ns = 0; ns < 2; ++ns)
            for (int r = 0; r < 4; ++r) {
                int m = wid * 32 + ms * 16 + quad * 4 + r;
                int n = ntile + ns * 16 + l15;
                atomicAdd(&z[(long)m * FOURU + n], acc[ms][ns][r]);
            }
}

// ---------------- K3: gates + LSTM cell, h -> d_out, c -> ws --------------
__global__ __launch_bounds__(256) void lstm_kernel(
    const float* __restrict__ z, const float* __restrict__ bias,
    const float* __restrict__ c_states, const int* __restrict__ sidx,
    float* __restrict__ h_out, float* __restrict__ c_buf)
{
    int e = blockIdx.x * 256 + threadIdx.x;   // 0..65535  (b*512 + u)
    int b = e >> 9;
    int u = e & 511;
    float zi = z[b * FOURU + u]          + bias[u];
    float zf = z[b * FOURU + 512 + u]    + bias[512 + u];
    float zg = z[b * FOURU + 1024 + u]   + bias[1024 + u];
    float zo = z[b * FOURU + 1536 + u]   + bias[1536 + u];
    float ig = 1.f / (1.f + expf(-zi));
    float fg = 1.f / (1.f + expf(-zf));
    float gg = tanhf(zg);
    float og = 1.f / (1.f + expf(-zo));
    float c0 = c_states[(long)sidx[b] * UNITS + u];
    float c  = fg * c0 + ig * gg;
    float h  = og * tanhf(c);
    h_out[e] = h;
    c_buf[e] = c;
}

// ---------------- K4: faithful diff_scatter (max-blend) -------------------
__global__ __launch_bounds__(256) void scatter_kernel(
    const float* __restrict__ h_states, const float* __restrict__ c_states,
    const float* __restrict__ h_new, const float* __restrict__ c_new,
    const int* __restrict__ sidx,
    float* __restrict__ out_h, float* __restrict__ out_c)
{
    __shared__ int s[BS];
    int t = threadIdx.x;
    if (t < BS) s[t] = sidx[t];
    __syncthreads();
    int j = blockIdx.x >> 1;                       // class (block-uniform)
    int u = (blockIdx.x & 1) * 256 + t;
    float mh = -INFINITY, mc = -INFINITY;
    int count = 0;
    for (int b = 0; b < BS; ++b) {
        if (s[b] == j) {                           // wave-uniform branch
            ++count;
            mh = fmaxf(mh, h_new[b * UNITS + u]);
            mc = fmaxf(mc, c_new[b * UNITS + u]);
        }
    }
    float ah = h_states[(long)j * UNITS + u];
    float ac = c_states[(long)j * UNITS + u];
    // count==BS: A never appears in the blend; count==0: mh=-inf -> A
    out_h[(long)j * UNITS + u] = (count == BS) ? mh : fmaxf(ah, mh);
    out_c[(long)j * UNITS + u] = (count == BS) ? mc : fmaxf(ac, mc);
}

extern "C" void kernel_launch(void* const* d_in, const int* in_sizes, int n_in,
                              void* d_out, int out_size, void* d_ws, size_t ws_size,
                              hipStream_t stream)
{
    (void)in_sizes; (void)n_in; (void)out_size; (void)ws_size;
    const float* x      = (const float*)d_in[0];
    const float* logits = (const float*)d_in[1];
    const float* h_st   = (const float*)d_in[2];
    const float* c_st   = (const float*)d_in[3];
    const float* kern   = (const float*)d_in[4];
    const float* reck   = (const float*)d_in[5];
    const float* bias   = (const float*)d_in[6];

    float* out        = (float*)d_out;
    float* out_h_step = out;                         // (128,512)
    float* out_newh   = out + BS * UNITS;            // (1024,512)
    float* out_newc   = out + BS * UNITS + NC * UNITS;

    char*  ws   = (char*)d_ws;
    int*   sidx = (int*)ws;                          // 512 B
    float* z    = (float*)(ws + 512);                // 128*2048*4 = 1 MB
    float* cbuf = (float*)(ws + 512 + BS * FOURU * sizeof(float));  // 256 KB

    hipMemsetAsync(z, 0, BS * FOURU * sizeof(float), stream);
    argmax_kernel <<<BS, 256, 0, stream>>>(logits, sidx);
    gemm_kernel   <<<dim3(FOURU / NT, 4), 256, 0, stream>>>(x, h_st, kern, reck, sidx, z);
    lstm_kernel   <<<BS * UNITS / 256, 256, 0, stream>>>(z, bias, c_st, sidx, out_h_step, cbuf);
    scatter_kernel<<<NC * UNITS / 256, 256, 0, stream>>>(h_st, c_st, out_h_step, cbuf, sidx,
                                                         out_newh, out_newc);
}

// Round 2
// 105.778 us; speedup vs baseline: 1.0998x; 1.0998x over previous
//
#include <hip/hip_runtime.h>
#include <hip/hip_bf16.h>
#include <math.h>

#define BS    128
#define NC    1024
#define UNITS 512
#define FEAT  512
#define FOURU 2048
#define KG    8          // k-groups for the gemm split (1024/8 = 128 per group)
#define NT    32         // n-columns per gemm block
#define WPAD  40         // wst leading dim (80 B rows, 16B-aligned, 2-way max alias)

typedef short  bf16x8 __attribute__((ext_vector_type(8)));
typedef float  f32x4  __attribute__((ext_vector_type(4)));

// round-half-up bf16: error <= 0.5 ulp (same bound as RNE), 2 ops/elem
__device__ __forceinline__ unsigned short bf_rhu(float f) {
    union { float f; unsigned u; } v; v.f = f;
    return (unsigned short)((v.u + 0x8000u) >> 16);
}
__device__ __forceinline__ unsigned pack2(float a, float b) {
    return (unsigned)bf_rhu(a) | ((unsigned)bf_rhu(b) << 16);
}

// ---- K1: per-row argmax + build A_bf16 = [x | h_states[argmax]] ---------
__global__ __launch_bounds__(256) void argmax_prep_kernel(
    const float* __restrict__ logits, const float* __restrict__ x,
    const float* __restrict__ h_states,
    int* __restrict__ sidx, unsigned* __restrict__ Abf /* uint view, 512/row */)
{
    int b = blockIdx.x;
    int t = threadIdx.x;
    float best = -INFINITY; int bi = 0;
    for (int i = t; i < NC; i += 256) {
        float v = logits[b * NC + i];
        if (v > best) { best = v; bi = i; }
    }
    for (int off = 32; off > 0; off >>= 1) {
        float ov = __shfl_down(best, off);
        int   oi = __shfl_down(bi, off);
        if (ov > best || (ov == best && oi < bi)) { best = ov; bi = oi; }
    }
    __shared__ float sv[4]; __shared__ int si[4];
    __shared__ int sbi;
    int wid = t >> 6;
    if ((t & 63) == 0) { sv[wid] = best; si[wid] = bi; }
    __syncthreads();
    if (t == 0) {
        for (int w = 1; w < 4; ++w)
            if (sv[w] > best || (sv[w] == best && si[w] < bi)) { best = sv[w]; bi = si[w]; }
        sidx[b] = bi;
        sbi = bi;
    }
    __syncthreads();
    // convert: threads 0..127 -> x row, 128..255 -> gathered h row
    int st = t & 127;
    const float* srcrow = (t < 128) ? (x + (long)b * FEAT)
                                    : (h_states + (long)sbi * UNITS);
    float4 v = *(const float4*)(srcrow + st * 4);
    unsigned lo = pack2(v.x, v.y), hi = pack2(v.z, v.w);
    // uint index within row: x half at 0..255, h half at 256..511
    unsigned du = (unsigned)b * 512u + (t < 128 ? 0u : 256u) + (unsigned)st * 2u;
    *(uint2*)(Abf + du) = make_uint2(lo, hi);
}

// ---- K2: z_part[kg] = A_bf16[:, kslice] @ W[kslice, :] (bf16 MFMA) -------
// grid (64 n-tiles, 8 k-groups), 256 threads. No atomics: each block writes
// its own 128x32 f32 tile of z_part[kg].
__global__ __launch_bounds__(256) void gemm_kernel(
    const unsigned short* __restrict__ Abf,   // [128][1024] bf16
    const float* __restrict__ kern, const float* __restrict__ reck,
    float* __restrict__ z_part)               // [KG][128][2048] f32
{
    // A tile stored as 16-B granules with XOR swizzle: granule(m, chunk p)
    // holds k-chunk c = (p ^ (m>>1)) & 3  -> frag reads are 2-way (free)
    __shared__ __align__(16) unsigned short as[BS * 32];   // 8 KB
    __shared__ __align__(16) unsigned short wst[NT * WPAD]; // [n][k] 2.5 KB

    int t = threadIdx.x;
    int ntile = blockIdx.x * NT;
    int kg = blockIdx.y;
    const float* W = (kg < 4) ? kern : reck;
    int wk0base = (kg & 3) * 128;   // k offset inside the weight matrix
    int k0base  = kg * 128;         // k offset inside A (1024 wide)

    int wid = t >> 6, lane = t & 63;
    int l15 = lane & 15, quad = lane >> 4;

    f32x4 zero = {0.f, 0.f, 0.f, 0.f};
    f32x4 acc[2][2] = {{zero, zero}, {zero, zero}};

    for (int kstep = 0; kstep < 4; ++kstep) {
        int k0  = k0base  + kstep * 32;
        int wk0 = wk0base + kstep * 32;

        // stage A: 512 granules, 2 per thread, 16-B vector load + store
        for (int r = 0; r < 2; ++r) {
            int G = r * 256 + t;
            int m = G >> 2;
            int p = G & 3;
            int c = (p ^ (m >> 1)) & 3;
            bf16x8 v = *(const bf16x8*)(Abf + (long)m * 1024 + k0 + c * 8);
            *(bf16x8*)&as[G * 8] = v;
        }
        // stage W^T (f32 -> bf16): wst[n][kk]
        for (int p = 0; p < 4; ++p) {
            int kk = (t >> 5) + p * 8;
            int n  = t & 31;
            wst[n * WPAD + kk] = bf_rhu(W[(long)(wk0 + kk) * FOURU + ntile + n]);
        }
        __syncthreads();

        bf16x8 afrag[2], bfrag[2];
        for (int ms = 0; ms < 2; ++ms) {
            int m = wid * 32 + ms * 16 + l15;
            afrag[ms] = *(const bf16x8*)&as[(m * 4 + ((quad ^ (m >> 1)) & 3)) * 8];
        }
        for (int ns = 0; ns < 2; ++ns) {
            int n = ns * 16 + l15;
            bfrag[ns] = *(const bf16x8*)&wst[n * WPAD + quad * 8];
        }
        for (int ms = 0; ms < 2; ++ms)
            for (int ns = 0; ns < 2; ++ns)
                acc[ms][ns] = __builtin_amdgcn_mfma_f32_16x16x32_bf16(
                                  afrag[ms], bfrag[ns], acc[ms][ns], 0, 0, 0);
        __syncthreads();
    }

    // C/D layout: col = lane&15, row = quad*4 + reg
    float* zp = z_part + (long)kg * BS * FOURU;
    for (int ms = 0; ms < 2; ++ms)
        for (int ns = 0; ns < 2; ++ns)
            for (int r = 0; r < 4; ++r) {
                int m = wid * 32 + ms * 16 + quad * 4 + r;
                int n = ntile + ns * 16 + l15;
                zp[(long)m * FOURU + n] = acc[ms][ns][r];
            }
}

// ---- K3: fused LSTM + diff_scatter --------------------------------------
// Block (j, u-half). Each row b belongs to exactly one class j = sidx[b], so
// the LSTM for (b,u) runs exactly once, inside the block owning class j.
__global__ __launch_bounds__(256) void scatter_lstm_kernel(
    const float* __restrict__ z_part, const float* __restrict__ bias,
    const float* __restrict__ h_states, const float* __restrict__ c_states,
    const int* __restrict__ sidx,
    float* __restrict__ h_out, float* __restrict__ out_h, float* __restrict__ out_c)
{
    __shared__ int s[BS];
    int t = threadIdx.x;
    if (t < BS) s[t] = sidx[t];
    __syncthreads();
    int j = blockIdx.x >> 1;
    int u = (blockIdx.x & 1) * 256 + t;

    float ah = h_states[(long)j * UNITS + u];
    float ac = c_states[(long)j * UNITS + u];   // == c0 for any matching b

    float mh = -INFINITY, mc = -INFINITY;
    int count = 0;
    float bi_ = bias[u], bf_ = bias[512 + u], bg_ = bias[1024 + u], bo_ = bias[1536 + u];

    for (int b = 0; b < BS; ++b) {
        if (s[b] == j) {                          // block-uniform branch
            ++count;
            float zi = bi_, zf = bf_, zg = bg_, zo = bo_;
            #pragma unroll
            for (int kg = 0; kg < KG; ++kg) {
                const float* zp = z_part + (long)kg * BS * FOURU + (long)b * FOURU;
                zi += zp[u];
                zf += zp[512 + u];
                zg += zp[1024 + u];
                zo += zp[1536 + u];
            }
            float ig = 1.f / (1.f + expf(-zi));
            float fg = 1.f / (1.f + expf(-zf));
            float gg = tanhf(zg);
            float og = 1.f / (1.f + expf(-zo));
            float c  = fg * ac + ig * gg;
            float h  = og * tanhf(c);
            h_out[(long)b * UNITS + u] = h;
            mh = fmaxf(mh, h);
            mc = fmaxf(mc, c);
        }
    }
    // count==BS: old state never appears in the blend; count==0 -> old state
    out_h[(long)j * UNITS + u] = (count == BS) ? mh : fmaxf(ah, mh);
    out_c[(long)j * UNITS + u] = (count == BS) ? mc : fmaxf(ac, mc);
}

extern "C" void kernel_launch(void* const* d_in, const int* in_sizes, int n_in,
                              void* d_out, int out_size, void* d_ws, size_t ws_size,
                              hipStream_t stream)
{
    (void)in_sizes; (void)n_in; (void)out_size; (void)ws_size;
    const float* x      = (const float*)d_in[0];
    const float* logits = (const float*)d_in[1];
    const float* h_st   = (const float*)d_in[2];
    const float* c_st   = (const float*)d_in[3];
    const float* kern   = (const float*)d_in[4];
    const float* reck   = (const float*)d_in[5];
    const float* bias   = (const float*)d_in[6];

    float* out        = (float*)d_out;
    float* out_h_step = out;                          // (128,512)
    float* out_newh   = out + BS * UNITS;             // (1024,512)
    float* out_newc   = out + BS * UNITS + NC * UNITS;

    char*     ws     = (char*)d_ws;
    int*      sidx   = (int*)ws;                               // 512 B
    unsigned* Abf    = (unsigned*)(ws + 1024);                 // 256 KB (bf16 view)
    float*    z_part = (float*)(ws + 1024 * 1024);             // 8 MB

    argmax_prep_kernel<<<BS, 256, 0, stream>>>(logits, x, h_st, sidx, Abf);
    gemm_kernel<<<dim3(FOURU / NT, KG), 256, 0, stream>>>(
        (const unsigned short*)Abf, kern, reck, z_part);
    scatter_lstm_kernel<<<NC * UNITS / 256, 256, 0, stream>>>(
        z_part, bias, h_st, c_st, sidx, out_h_step, out_newh, out_newc);
}